// Round 1
// baseline (800.948 us; speedup 1.0000x reference)
//
#include <hip/hip_runtime.h>
#include <math.h>

// Problem constants (fixed by setup_inputs)
#define NQRY 8192   // queries
#define DIM  256    // d
#define MS   4608   // memory slots m
#define NQE  16384  // Nq embeddings
#define NBLK 8      // m // (C-1) partitions -> 8 blocks of 576
#define PRROWS 576

// d_out scratch layout (in floats). Everything here is consumed before the
// final k_read kernel overwrites the whole of d_out with the real output.
static const size_t Q_OFF   = (size_t)NQRY * MS;            // q (normalized queries)
static const size_t QU_OFF  = Q_OFF + (size_t)NQRY * DIM;   // qu scatter buffer
static const size_t CM_OFF  = QU_OFF + (size_t)MS * DIM;    // colmax (ordered u32)
static const size_t MEM_OFF = CM_OFF + MS;                  // updated memory rows
// end = 42,209,792 floats < out_size (67,108,864)

// Order-preserving float<->uint mapping for atomicMax on floats
__device__ __forceinline__ unsigned ordf(float f) {
  unsigned u = __float_as_uint(f);
  return (u & 0x80000000u) ? ~u : (u | 0x80000000u);
}
__device__ __forceinline__ float unordf(unsigned u) {
  unsigned b = (u & 0x80000000u) ? (u & 0x7FFFFFFFu) : ~u;
  return __uint_as_float(b);
}

// K1: l2-normalize query rows
__global__ __launch_bounds__(256) void k_qnorm(const float* __restrict__ query,
                                               float* __restrict__ q) {
  int i = blockIdx.x, t = threadIdx.x;
  float x = query[(size_t)i * DIM + t];
  float v = x * x;
  #pragma unroll
  for (int o = 32; o; o >>= 1) v += __shfl_down(v, o);
  __shared__ float s[4];
  if ((t & 63) == 0) s[t >> 6] = v;
  __syncthreads();
  float ss = (s[0] + s[1]) + (s[2] + s[3]);
  q[(size_t)i * DIM + t] = x / fmaxf(sqrtf(ss), 1e-12f);
}

// K2: S = q @ keys^T  (f32, 128x128 tile, 8x8 micro, BK=16)
__global__ __launch_bounds__(256) void k_score(const float* __restrict__ A,
                                               const float* __restrict__ B,
                                               float* __restrict__ S) {
  __shared__ float As[16][132];
  __shared__ float Bs[16][132];
  int tid = threadIdx.x;
  int tx = tid & 15, ty = tid >> 4;
  int lrow = tid >> 2;        // 0..63
  int lk = (tid & 3) * 4;     // 0,4,8,12
  const float* Ab = A + (size_t)(blockIdx.y * 128) * DIM;
  const float* Bb = B + (size_t)(blockIdx.x * 128) * DIM;
  float acc[8][8] = {};
  for (int kk = 0; kk < DIM; kk += 16) {
    float4 a0 = *(const float4*)(Ab + (size_t)lrow * DIM + kk + lk);
    float4 a1 = *(const float4*)(Ab + (size_t)(lrow + 64) * DIM + kk + lk);
    float4 b0 = *(const float4*)(Bb + (size_t)lrow * DIM + kk + lk);
    float4 b1 = *(const float4*)(Bb + (size_t)(lrow + 64) * DIM + kk + lk);
    __syncthreads();
    As[lk+0][lrow] = a0.x; As[lk+1][lrow] = a0.y; As[lk+2][lrow] = a0.z; As[lk+3][lrow] = a0.w;
    As[lk+0][lrow+64] = a1.x; As[lk+1][lrow+64] = a1.y; As[lk+2][lrow+64] = a1.z; As[lk+3][lrow+64] = a1.w;
    Bs[lk+0][lrow] = b0.x; Bs[lk+1][lrow] = b0.y; Bs[lk+2][lrow] = b0.z; Bs[lk+3][lrow] = b0.w;
    Bs[lk+0][lrow+64] = b1.x; Bs[lk+1][lrow+64] = b1.y; Bs[lk+2][lrow+64] = b1.z; Bs[lk+3][lrow+64] = b1.w;
    __syncthreads();
    #pragma unroll
    for (int k = 0; k < 16; k++) {
      float ar[8], br[8];
      *(float4*)&ar[0] = *(const float4*)&As[k][ty * 8];
      *(float4*)&ar[4] = *(const float4*)&As[k][ty * 8 + 4];
      *(float4*)&br[0] = *(const float4*)&Bs[k][tx * 8];
      *(float4*)&br[4] = *(const float4*)&Bs[k][tx * 8 + 4];
      #pragma unroll
      for (int r = 0; r < 8; r++)
        #pragma unroll
        for (int s2 = 0; s2 < 8; s2++)
          acc[r][s2] = fmaf(ar[r], br[s2], acc[r][s2]);
    }
  }
  #pragma unroll
  for (int r = 0; r < 8; r++) {
    size_t ig = (size_t)blockIdx.y * 128 + ty * 8 + r;
    float* Sp = S + ig * MS + blockIdx.x * 128 + tx * 8;
    *(float4*)(Sp + 0) = *(float4*)&acc[r][0];
    *(float4*)(Sp + 4) = *(float4*)&acc[r][4];
  }
}

// K3: column max of S (ordered-uint atomicMax; colmax pre-zeroed = -inf)
__global__ __launch_bounds__(256) void k_colmax(const float* __restrict__ S,
                                                unsigned* __restrict__ colmax) {
  int j = blockIdx.x * 256 + threadIdx.x;
  int r0 = blockIdx.y * 512;
  float m = -INFINITY;
  for (int i = 0; i < 512; i++) m = fmaxf(m, S[(size_t)(r0 + i) * MS + j]);
  atomicMax(colmax + j, ordf(m));
}

// K4: label-derived scalars (last, count, class_counts[last], active mask)
__global__ void k_scalars(const int* __restrict__ labels,
                          const float* __restrict__ cc,
                          float* __restrict__ sc) {
  int t = threadIdx.x;
  int l = (t < 16) ? labels[t] : (int)0x80000000;
  int mx = l;
  #pragma unroll
  for (int o = 32; o; o >>= 1) mx = max(mx, __shfl_down(mx, o));
  mx = __shfl(mx, 0);
  int cnt = (t < 16 && l == mx) ? 1 : 0;
  #pragma unroll
  for (int o = 32; o; o >>= 1) cnt += __shfl_down(cnt, o);
  unsigned amv = (t < 16) ? (1u << l) : 0u;
  #pragma unroll
  for (int o = 32; o; o >>= 1) amv |= __shfl_down(amv, o);
  if (t == 0) {
    sc[0] = __int_as_float(mx);
    sc[1] = (float)cnt;
    sc[2] = cc[mx];
    sc[3] = __uint_as_float(amv);
  }
}

// K5: per-row argmax (first-index tie-break, matching jnp.argmax) + scatter
// qu[g] += exp(S[i,g] - colmax[g]) * q[i]
__global__ __launch_bounds__(256) void k_rowscatter(const float* __restrict__ S,
                                                    const unsigned* __restrict__ colmax,
                                                    const float* __restrict__ q,
                                                    float* __restrict__ qu) {
  int i = blockIdx.x, t = threadIdx.x;
  const float* Sr = S + (size_t)i * MS;
  unsigned long long best = 0ull;
  for (int j = t; j < MS; j += 256) {
    unsigned long long p =
        ((unsigned long long)ordf(Sr[j]) << 32) | (unsigned long long)(0xFFFFFFFFu - (unsigned)j);
    best = p > best ? p : best;
  }
  #pragma unroll
  for (int o = 32; o; o >>= 1) {
    unsigned long long ob = __shfl_down(best, o);
    best = ob > best ? ob : best;
  }
  __shared__ unsigned long long sb[4];
  if ((t & 63) == 0) sb[t >> 6] = best;
  __syncthreads();
  best = sb[0];
  if (sb[1] > best) best = sb[1];
  if (sb[2] > best) best = sb[2];
  if (sb[3] > best) best = sb[3];
  int g = (int)(0xFFFFFFFFu - (unsigned)(best & 0xFFFFFFFFull));
  float sv = unordf((unsigned)(best >> 32));
  float w = expf(sv - unordf(colmax[g]));
  atomicAdd(qu + (size_t)g * DIM + t, w * q[(size_t)i * DIM + t]);
}

// K6: mem = l2norm((temp*keys + qu*active) / temp2)
__global__ __launch_bounds__(256) void k_mem(const float* __restrict__ keys,
                                             const float* __restrict__ qu,
                                             const float* __restrict__ sc,
                                             float* __restrict__ mem) {
  int j = blockIdx.x, t = threadIdx.x;
  int last = __float_as_int(sc[0]);
  float count = sc[1], ccl = sc[2];
  unsigned am = __float_as_uint(sc[3]);
  int cls = j >> 9;  // part = 4608/9 = 512
  bool inp = (cls == last);
  float temp = inp ? ccl : 1.0f;
  float quv = ((am >> cls) & 1u) ? qu[(size_t)j * DIM + t] : 0.0f;
  float u = temp * keys[(size_t)j * DIM + t] + quv;
  float temp2 = temp + (inp ? count : 0.0f);
  float v = u / temp2;
  float vv = v * v;
  #pragma unroll
  for (int o = 32; o; o >>= 1) vv += __shfl_down(vv, o);
  __shared__ float s[4];
  if ((t & 63) == 0) s[t >> 6] = vv;
  __syncthreads();
  float ss = (s[0] + s[1]) + (s[2] + s[3]);
  mem[(size_t)j * DIM + t] = v / fmaxf(sqrtf(ss), 1e-12f);
}

// K7: G_b = B_b^T B_b  (8 Gram matrices, 256x256, K=576)
__global__ __launch_bounds__(256) void k_gram(const float* __restrict__ mem,
                                              float* __restrict__ G) {
  __shared__ float As[16][64];
  __shared__ float Bs[16][64];
  int b = blockIdx.z;
  int kxc = blockIdx.x * 64;  // col tile
  int kyr = blockIdx.y * 64;  // row tile
  const float* Ab = mem + (size_t)b * PRROWS * DIM;
  int tid = threadIdx.x, tx = tid & 15, ty = tid >> 4;
  int lp = tid >> 4;          // 0..15
  int lk = (tid & 15) * 4;    // 0..60
  float acc[4][4] = {};
  for (int p0 = 0; p0 < PRROWS; p0 += 16) {
    float4 av = *(const float4*)(Ab + (size_t)(p0 + lp) * DIM + kyr + lk);
    float4 bv = *(const float4*)(Ab + (size_t)(p0 + lp) * DIM + kxc + lk);
    __syncthreads();
    *(float4*)&As[lp][lk] = av;
    *(float4*)&Bs[lp][lk] = bv;
    __syncthreads();
    #pragma unroll
    for (int p = 0; p < 16; p++) {
      float a[4], c[4];
      *(float4*)&a[0] = *(const float4*)&As[p][ty * 4];
      *(float4*)&c[0] = *(const float4*)&Bs[p][tx * 4];
      #pragma unroll
      for (int r = 0; r < 4; r++)
        #pragma unroll
        for (int s2 = 0; s2 < 4; s2++)
          acc[r][s2] = fmaf(a[r], c[s2], acc[r][s2]);
    }
  }
  #pragma unroll
  for (int r = 0; r < 4; r++)
    #pragma unroll
    for (int s2 = 0; s2 < 4; s2++)
      G[(size_t)b * DIM * DIM + (size_t)(kyr + ty * 4 + r) * DIM + kxc + tx * 4 + s2] = acc[r][s2];
}

// K8: out[e,b,n,:] = Q_e[n,:] @ G_b  where Q_e[n,k] = emb_e[k,n]
__global__ __launch_bounds__(256) void k_read(const float* __restrict__ embS,
                                              const float* __restrict__ embT,
                                              const float* __restrict__ G,
                                              float* __restrict__ out) {
  __shared__ float As[16][128];  // [k][n]
  __shared__ float Bs[16][64];   // [k][dd]
  int eb = blockIdx.z;
  const float* emb = (eb >> 3) ? embT : embS;
  const float* Gb = G + (size_t)(eb & 7) * DIM * DIM;
  int n0 = blockIdx.x * 128;
  int d0 = blockIdx.y * 64;
  int tid = threadIdx.x;
  int tx = tid & 15, ty = tid >> 4;
  int ak = tid >> 5;          // 0..7
  int an = (tid & 31) * 4;    // 0..124
  int bk = tid >> 4;          // 0..15
  int bd = (tid & 15) * 4;    // 0..60
  float acc[8][4] = {};
  for (int kk = 0; kk < DIM; kk += 16) {
    float4 a0 = *(const float4*)(emb + (size_t)(kk + ak) * NQE + n0 + an);
    float4 a1 = *(const float4*)(emb + (size_t)(kk + ak + 8) * NQE + n0 + an);
    float4 b0 = *(const float4*)(Gb + (size_t)(kk + bk) * DIM + d0 + bd);
    __syncthreads();
    *(float4*)&As[ak][an] = a0;
    *(float4*)&As[ak + 8][an] = a1;
    *(float4*)&Bs[bk][bd] = b0;
    __syncthreads();
    #pragma unroll
    for (int k = 0; k < 16; k++) {
      float ar[8], br[4];
      *(float4*)&ar[0] = *(const float4*)&As[k][ty * 8];
      *(float4*)&ar[4] = *(const float4*)&As[k][ty * 8 + 4];
      *(float4*)&br[0] = *(const float4*)&Bs[k][tx * 4];
      #pragma unroll
      for (int r = 0; r < 8; r++)
        #pragma unroll
        for (int s2 = 0; s2 < 4; s2++)
          acc[r][s2] = fmaf(ar[r], br[s2], acc[r][s2]);
    }
  }
  size_t base = (size_t)eb * NQE * DIM;
  #pragma unroll
  for (int r = 0; r < 8; r++) {
    float* op = out + base + (size_t)(n0 + ty * 8 + r) * DIM + d0 + tx * 4;
    *(float4*)op = *(float4*)&acc[r][0];
  }
}

extern "C" void kernel_launch(void* const* d_in, const int* in_sizes, int n_in,
                              void* d_out, int out_size, void* d_ws, size_t ws_size,
                              hipStream_t stream) {
  const float* query  = (const float*)d_in[0];
  const float* embS   = (const float*)d_in[1];
  const float* embT   = (const float*)d_in[2];
  const float* keys   = (const float*)d_in[3];
  const float* cc     = (const float*)d_in[4];
  const int*   labels = (const int*)d_in[5];
  float* out = (float*)d_out;

  // scratch inside d_out (all dead before k_read overwrites everything)
  float* S  = out;                 // 8192*4608 score matrix
  float* q  = out + Q_OFF;
  float* qu = out + QU_OFF;
  unsigned* colmax = (unsigned*)(out + CM_OFF);
  float* mem = out + MEM_OFF;
  // d_ws: G (8*256*256 f32 = 2 MB) + 4 scalar slots
  float* G  = (float*)d_ws;
  float* sc = G + (size_t)NBLK * DIM * DIM;

  // zero qu + colmax (contiguous); ordered-uint 0 == -inf identity
  hipMemsetAsync(qu, 0, ((size_t)MS * DIM + MS) * sizeof(float), stream);

  k_qnorm<<<NQRY, 256, 0, stream>>>(query, q);
  k_score<<<dim3(MS / 128, NQRY / 128), 256, 0, stream>>>(q, keys, S);
  k_colmax<<<dim3(MS / 256, NQRY / 512), 256, 0, stream>>>(S, colmax);
  k_scalars<<<1, 64, 0, stream>>>(labels, cc, sc);
  k_rowscatter<<<NQRY, 256, 0, stream>>>(S, colmax, q, qu);
  k_mem<<<MS, 256, 0, stream>>>(keys, qu, sc, mem);
  k_gram<<<dim3(4, 4, NBLK), 256, 0, stream>>>(mem, G);
  k_read<<<dim3(NQE / 128, DIM / 64, 2 * NBLK), 256, 0, stream>>>(embS, embT, G, out);
}

// Round 2
// 290.881 us; speedup vs baseline: 2.7535x; 2.7535x over previous
//
#include <hip/hip_runtime.h>
#include <math.h>

// Problem constants (fixed by setup_inputs)
#define NQRY 8192   // queries
#define DIM  256    // d
#define MS   4608   // memory slots m
#define NQE  16384  // Nq embeddings
#define NBLK 8      // m // (C-1) partitions -> 8 blocks of 576
#define PRROWS 576

typedef __attribute__((ext_vector_type(8))) short bf16x8;
typedef __attribute__((ext_vector_type(4))) float f32x4;

// ---- d_out scratch layout (float offsets). All scratch is dead before
// k_read_mfma overwrites the entire output buffer. ----
// q f32          [8192][256]            @ 0          (2,097,152 fl)
// qh bf16        [8192][256]            @ 2,097,152  (1,048,576 fl)
// ql bf16        [8192][256]            @ 3,145,728
// kh bf16        [4608][256]            @ 4,194,304  (589,824 fl)
// kl bf16        [4608][256]            @ 4,784,128
// qu f32         [4608][256]            @ 5,373,952  (1,179,648 fl)
// rowbest u64    [8192]                 @ 6,553,600  (16,384 fl)
// colmax u32     [4608]                 @ 6,569,984  (4,608 fl)
// memr f32       [4608][256]            @ 6,574,592  (ends 7,754,240 < 67,108,864)

// Order-preserving float<->uint mapping for atomicMax on floats
__device__ __forceinline__ unsigned ordf(float f) {
  unsigned u = __float_as_uint(f);
  return (u & 0x80000000u) ? ~u : (u | 0x80000000u);
}
__device__ __forceinline__ float unordf(unsigned u) {
  unsigned b = (u & 0x80000000u) ? (u & 0x7FFFFFFFu) : ~u;
  return __uint_as_float(b);
}
// round-to-nearest-even f32 -> bf16 bits
__device__ __forceinline__ unsigned short bf16rn(float x) {
  unsigned u = __float_as_uint(x);
  unsigned r = u + 0x7FFFu + ((u >> 16) & 1u);
  return (unsigned short)(r >> 16);
}
// split: x = hi(bf16, trunc) + lo(bf16, RN); residual <= 2^-17 |x|
__device__ __forceinline__ void splitbf(float x, unsigned short& h, unsigned short& lo) {
  unsigned u = __float_as_uint(x);
  h = (unsigned short)(u >> 16);
  float hf = __uint_as_float(u & 0xFFFF0000u);
  lo = bf16rn(x - hf);
}

// K1: l2-normalize query rows, emit f32 + bf16 hi/lo splits
__global__ __launch_bounds__(256) void k_qnorm(const float* __restrict__ query,
                                               float* __restrict__ q,
                                               unsigned short* __restrict__ qh,
                                               unsigned short* __restrict__ ql) {
  int i = blockIdx.x, t = threadIdx.x;
  size_t idx = (size_t)i * DIM + t;
  float x = query[idx];
  float v = x * x;
  #pragma unroll
  for (int o = 32; o; o >>= 1) v += __shfl_down(v, o);
  __shared__ float s[4];
  if ((t & 63) == 0) s[t >> 6] = v;
  __syncthreads();
  float ss = (s[0] + s[1]) + (s[2] + s[3]);
  float qq = x / fmaxf(sqrtf(ss), 1e-12f);
  q[idx] = qq;
  unsigned short h, lo;
  splitbf(qq, h, lo);
  qh[idx] = h; ql[idx] = lo;
}

// K2: split keys to bf16 hi/lo
__global__ __launch_bounds__(256) void k_ksplit(const float* __restrict__ keys,
                                                unsigned short* __restrict__ kh,
                                                unsigned short* __restrict__ kl) {
  size_t idx = (size_t)blockIdx.x * 256 + threadIdx.x;
  unsigned short h, lo;
  splitbf(keys[idx], h, lo);
  kh[idx] = h; kl[idx] = lo;
}

// K3: label-derived scalars (last, count, class_counts[last], active mask)
__global__ void k_scalars(const int* __restrict__ labels,
                          const float* __restrict__ cc,
                          float* __restrict__ sc) {
  int t = threadIdx.x;
  int l = (t < 16) ? labels[t] : (int)0x80000000;
  int mx = l;
  #pragma unroll
  for (int o = 32; o; o >>= 1) mx = max(mx, __shfl_down(mx, o));
  mx = __shfl(mx, 0);
  int cnt = (t < 16 && l == mx) ? 1 : 0;
  #pragma unroll
  for (int o = 32; o; o >>= 1) cnt += __shfl_down(cnt, o);
  unsigned amv = (t < 16) ? (1u << l) : 0u;
  #pragma unroll
  for (int o = 32; o; o >>= 1) amv |= __shfl_down(amv, o);
  if (t == 0) {
    sc[0] = __int_as_float(mx);
    sc[1] = (float)cnt;
    sc[2] = cc[mx];
    sc[3] = __uint_as_float(amv);
  }
}

// K4: fused score GEMM (split-bf16 3-pass MFMA) + row-argmax/col-max epilogue.
// No S matrix is ever stored. rowbest: packed (ordf(val)<<32)|(~col) u64 atomicMax.
__global__ __launch_bounds__(256) void k_scoremax(
    const unsigned short* __restrict__ qh, const unsigned short* __restrict__ ql,
    const unsigned short* __restrict__ kh, const unsigned short* __restrict__ kl,
    unsigned long long* __restrict__ rowbest, unsigned* __restrict__ colmax) {
  __shared__ __align__(16) char smem[65536];
  char* sAh = smem;          char* sAl = smem + 16384;
  char* sBh = smem + 32768;  char* sBl = smem + 49152;
  int tid = threadIdx.x;
  int n0 = blockIdx.x * 128, m0 = blockIdx.y * 128;
  int w = tid >> 6, l = tid & 63;
  int wm = w >> 1, wn = w & 1;
  int lr = l >> 4, lc = l & 15;
  f32x4 acc[4][4] = {};
  for (int kk = 0; kk < 4; kk++) {
    __syncthreads();
    #pragma unroll
    for (int t = 0; t < 4; t++) {
      int c = t * 256 + tid;            // 16B chunk id, 0..1023
      int row = c >> 3, cc = c & 7;
      int ldsb = row * 128 + ((cc * 16) ^ ((row & 7) << 4));  // T2 swizzle
      size_t gA = (size_t)(m0 + row) * DIM + kk * 64 + cc * 8;
      size_t gB = (size_t)(n0 + row) * DIM + kk * 64 + cc * 8;
      *(bf16x8*)(sAh + ldsb) = *(const bf16x8*)(qh + gA);
      *(bf16x8*)(sAl + ldsb) = *(const bf16x8*)(ql + gA);
      *(bf16x8*)(sBh + ldsb) = *(const bf16x8*)(kh + gB);
      *(bf16x8*)(sBl + ldsb) = *(const bf16x8*)(kl + gB);
    }
    __syncthreads();
    #pragma unroll
    for (int st = 0; st < 2; st++) {
      bf16x8 ah[4], al[4], bh[4], bl[4];
      #pragma unroll
      for (int f = 0; f < 4; f++) {
        int ra = wm * 64 + f * 16 + lc;
        int ka = (st * 64 + lr * 16) ^ ((ra & 7) << 4);
        ah[f] = *(const bf16x8*)(sAh + ra * 128 + ka);
        al[f] = *(const bf16x8*)(sAl + ra * 128 + ka);
        int rb = wn * 64 + f * 16 + lc;
        int kb = (st * 64 + lr * 16) ^ ((rb & 7) << 4);
        bh[f] = *(const bf16x8*)(sBh + rb * 128 + kb);
        bl[f] = *(const bf16x8*)(sBl + rb * 128 + kb);
      }
      #pragma unroll
      for (int fm = 0; fm < 4; fm++)
        #pragma unroll
        for (int fn = 0; fn < 4; fn++) {
          acc[fm][fn] = __builtin_amdgcn_mfma_f32_16x16x32_bf16(ah[fm], bh[fn], acc[fm][fn], 0, 0, 0);
          acc[fm][fn] = __builtin_amdgcn_mfma_f32_16x16x32_bf16(ah[fm], bl[fn], acc[fm][fn], 0, 0, 0);
          acc[fm][fn] = __builtin_amdgcn_mfma_f32_16x16x32_bf16(al[fm], bh[fn], acc[fm][fn], 0, 0, 0);
        }
    }
  }
  // epilogue: row argmax (packed u64) + column max
  #pragma unroll
  for (int fm = 0; fm < 4; fm++) {
    #pragma unroll
    for (int rg = 0; rg < 4; rg++) {
      unsigned long long p = 0ull;
      #pragma unroll
      for (int fn = 0; fn < 4; fn++) {
        float v = acc[fm][fn][rg];
        unsigned ng = (unsigned)(n0 + wn * 64 + fn * 16 + lc);
        unsigned long long cand =
            ((unsigned long long)ordf(v) << 32) | (unsigned long long)(0xFFFFFFFFu - ng);
        if (cand > p) p = cand;
      }
      #pragma unroll
      for (int o = 1; o < 16; o <<= 1) {
        unsigned long long t2 = __shfl_xor(p, o);
        if (t2 > p) p = t2;
      }
      if (lc == 0)
        atomicMax(rowbest + (m0 + wm * 64 + fm * 16 + lr * 4 + rg), p);
    }
  }
  #pragma unroll
  for (int fn = 0; fn < 4; fn++) {
    float v = -3.4e38f;
    #pragma unroll
    for (int fm = 0; fm < 4; fm++)
      #pragma unroll
      for (int rg = 0; rg < 4; rg++) v = fmaxf(v, acc[fm][fn][rg]);
    v = fmaxf(v, __shfl_xor(v, 16));
    v = fmaxf(v, __shfl_xor(v, 32));
    if (lr == 0) atomicMax(colmax + (n0 + wn * 64 + fn * 16 + lc), ordf(v));
  }
}

// K5: per-query scatter using rowbest/colmax only (no S).
__global__ __launch_bounds__(256) void k_rowscatter(
    const unsigned long long* __restrict__ rowbest, const unsigned* __restrict__ colmax,
    const float* __restrict__ q, float* __restrict__ qu) {
  int i = blockIdx.x, t = threadIdx.x;
  unsigned long long p = rowbest[i];
  int g = (int)(0xFFFFFFFFu - (unsigned)(p & 0xFFFFFFFFull));
  float sv = unordf((unsigned)(p >> 32));
  float w = expf(sv - unordf(colmax[g]));
  atomicAdd(qu + (size_t)g * DIM + t, w * q[(size_t)i * DIM + t]);
}

// K6: mem = l2norm((temp*keys + qu*active) / temp2)
__global__ __launch_bounds__(256) void k_mem(const float* __restrict__ keys,
                                             const float* __restrict__ qu,
                                             const float* __restrict__ sc,
                                             float* __restrict__ memr) {
  int j = blockIdx.x, t = threadIdx.x;
  int last = __float_as_int(sc[0]);
  float count = sc[1], ccl = sc[2];
  unsigned am = __float_as_uint(sc[3]);
  int cls = j >> 9;  // part = 512
  bool inp = (cls == last);
  float temp = inp ? ccl : 1.0f;
  float quv = ((am >> cls) & 1u) ? qu[(size_t)j * DIM + t] : 0.0f;
  float u = temp * keys[(size_t)j * DIM + t] + quv;
  float temp2 = temp + (inp ? count : 0.0f);
  float v = u / temp2;
  float vv = v * v;
  #pragma unroll
  for (int o = 32; o; o >>= 1) vv += __shfl_down(vv, o);
  __shared__ float s[4];
  if ((t & 63) == 0) s[t >> 6] = vv;
  __syncthreads();
  float ss = (s[0] + s[1]) + (s[2] + s[3]);
  memr[(size_t)j * DIM + t] = v / fmaxf(sqrtf(ss), 1e-12f);
}

// K7: G_b = B_b^T B_b (f32 vector compute, small), emit hi/lo bf16 split.
__global__ __launch_bounds__(256) void k_gram(const float* __restrict__ memr,
                                              unsigned short* __restrict__ Gh,
                                              unsigned short* __restrict__ Gl) {
  __shared__ float As[16][64];
  __shared__ float Bs[16][64];
  int b = blockIdx.z;
  int kxc = blockIdx.x * 64;
  int kyr = blockIdx.y * 64;
  const float* Ab = memr + (size_t)b * PRROWS * DIM;
  int tid = threadIdx.x, tx = tid & 15, ty = tid >> 4;
  int lp = tid >> 4;
  int lk = (tid & 15) * 4;
  float acc[4][4] = {};
  for (int p0 = 0; p0 < PRROWS; p0 += 16) {
    float4 av = *(const float4*)(Ab + (size_t)(p0 + lp) * DIM + kyr + lk);
    float4 bv = *(const float4*)(Ab + (size_t)(p0 + lp) * DIM + kxc + lk);
    __syncthreads();
    *(float4*)&As[lp][lk] = av;
    *(float4*)&Bs[lp][lk] = bv;
    __syncthreads();
    #pragma unroll
    for (int p = 0; p < 16; p++) {
      float a[4], c[4];
      *(float4*)&a[0] = *(const float4*)&As[p][ty * 4];
      *(float4*)&c[0] = *(const float4*)&Bs[p][tx * 4];
      #pragma unroll
      for (int r = 0; r < 4; r++)
        #pragma unroll
        for (int s2 = 0; s2 < 4; s2++)
          acc[r][s2] = fmaf(a[r], c[s2], acc[r][s2]);
    }
  }
  #pragma unroll
  for (int r = 0; r < 4; r++)
    #pragma unroll
    for (int s2 = 0; s2 < 4; s2++) {
      size_t o = (size_t)b * DIM * DIM + (size_t)(kyr + ty * 4 + r) * DIM + kxc + tx * 4 + s2;
      unsigned short h, lo;
      splitbf(acc[r][s2], h, lo);
      Gh[o] = h; Gl[o] = lo;
    }
}

// K8: out[eb][n][d] = Q_e[n,:] @ G_b via split-bf16 3-pass MFMA.
// A (emb, [k][n] in memory) is transposed+split during staging.
__global__ __launch_bounds__(256) void k_read_mfma(
    const float* __restrict__ embS, const float* __restrict__ embT,
    const unsigned short* __restrict__ Gh, const unsigned short* __restrict__ Gl,
    float* __restrict__ out) {
  __shared__ __align__(16) char smem[65536];
  char* sAh = smem;          char* sAl = smem + 16384;
  char* sBh = smem + 32768;  char* sBl = smem + 49152;
  int tid = threadIdx.x;
  int eb = blockIdx.z;
  const float* emb = (eb >> 3) ? embT : embS;
  const unsigned short* gh = Gh + (size_t)(eb & 7) * DIM * DIM;
  const unsigned short* gl = Gl + (size_t)(eb & 7) * DIM * DIM;
  int n0 = blockIdx.x * 128, d0 = blockIdx.y * 128;
  int w = tid >> 6, l = tid & 63;
  int wm = w >> 1, wn = w & 1;
  int lr = l >> 4, lc = l & 15;
  int na = tid & 127, khalf = tid >> 7;
  f32x4 acc[4][4] = {};
  for (int kk = 0; kk < 4; kk++) {
    __syncthreads();
    // A staging: transpose + split 32 f32 per thread (row na, k-range khalf*32)
    {
      const float* ep = emb + (size_t)(kk * 64 + khalf * 32) * NQE + n0 + na;
      float xv[32];
      #pragma unroll
      for (int j = 0; j < 32; j++) xv[j] = ep[(size_t)j * NQE];
      #pragma unroll
      for (int c2 = 0; c2 < 4; c2++) {
        bf16x8 hv, lv;
        #pragma unroll
        for (int e = 0; e < 8; e++) {
          float x = xv[c2 * 8 + e];
          unsigned u = __float_as_uint(x);
          hv[e] = (short)(u >> 16);
          float hf = __uint_as_float(u & 0xFFFF0000u);
          lv[e] = (short)bf16rn(x - hf);
        }
        int kc = khalf * 4 + c2;
        int ldsb = na * 128 + ((kc * 16) ^ ((na & 7) << 4));
        *(bf16x8*)(sAh + ldsb) = hv;
        *(bf16x8*)(sAl + ldsb) = lv;
      }
    }
    // B staging: copy pre-split G tiles
    #pragma unroll
    for (int t = 0; t < 4; t++) {
      int c = t * 256 + tid;
      int row = c >> 3, cc = c & 7;
      int ldsb = row * 128 + ((cc * 16) ^ ((row & 7) << 4));
      size_t goff = (size_t)(d0 + row) * DIM + kk * 64 + cc * 8;
      *(bf16x8*)(sBh + ldsb) = *(const bf16x8*)(gh + goff);
      *(bf16x8*)(sBl + ldsb) = *(const bf16x8*)(gl + goff);
    }
    __syncthreads();
    #pragma unroll
    for (int st = 0; st < 2; st++) {
      bf16x8 ah[4], al[4], bh[4], bl[4];
      #pragma unroll
      for (int f = 0; f < 4; f++) {
        int ra = wm * 64 + f * 16 + lc;
        int ka = (st * 64 + lr * 16) ^ ((ra & 7) << 4);
        ah[f] = *(const bf16x8*)(sAh + ra * 128 + ka);
        al[f] = *(const bf16x8*)(sAl + ra * 128 + ka);
        int rb = wn * 64 + f * 16 + lc;
        int kb = (st * 64 + lr * 16) ^ ((rb & 7) << 4);
        bh[f] = *(const bf16x8*)(sBh + rb * 128 + kb);
        bl[f] = *(const bf16x8*)(sBl + rb * 128 + kb);
      }
      #pragma unroll
      for (int fm = 0; fm < 4; fm++)
        #pragma unroll
        for (int fn = 0; fn < 4; fn++) {
          acc[fm][fn] = __builtin_amdgcn_mfma_f32_16x16x32_bf16(ah[fm], bh[fn], acc[fm][fn], 0, 0, 0);
          acc[fm][fn] = __builtin_amdgcn_mfma_f32_16x16x32_bf16(ah[fm], bl[fn], acc[fm][fn], 0, 0, 0);
          acc[fm][fn] = __builtin_amdgcn_mfma_f32_16x16x32_bf16(al[fm], bh[fn], acc[fm][fn], 0, 0, 0);
        }
    }
  }
  size_t base = (size_t)eb * NQE * DIM;
  #pragma unroll
  for (int fm = 0; fm < 4; fm++)
    #pragma unroll
    for (int rg = 0; rg < 4; rg++) {
      int n = n0 + wm * 64 + fm * 16 + lr * 4 + rg;
      float* op = out + base + (size_t)n * DIM + d0 + wn * 64 + lc;
      #pragma unroll
      for (int fn = 0; fn < 4; fn++) op[fn * 16] = acc[fm][fn][rg];
    }
}

extern "C" void kernel_launch(void* const* d_in, const int* in_sizes, int n_in,
                              void* d_out, int out_size, void* d_ws, size_t ws_size,
                              hipStream_t stream) {
  const float* query  = (const float*)d_in[0];
  const float* embS   = (const float*)d_in[1];
  const float* embT   = (const float*)d_in[2];
  const float* keys   = (const float*)d_in[3];
  const float* cc     = (const float*)d_in[4];
  const int*   labels = (const int*)d_in[5];
  float* out = (float*)d_out;

  float* q                     = out;
  unsigned short* qh           = (unsigned short*)(out + 2097152);
  unsigned short* ql           = (unsigned short*)(out + 3145728);
  unsigned short* kh           = (unsigned short*)(out + 4194304);
  unsigned short* kl           = (unsigned short*)(out + 4784128);
  float* qu                    = out + 5373952;
  unsigned long long* rowbest  = (unsigned long long*)(out + 6553600);
  unsigned* colmax             = (unsigned*)(out + 6569984);
  float* memr                  = out + 6574592;

  unsigned short* Gh = (unsigned short*)d_ws;                 // 1 MB
  unsigned short* Gl = Gh + (size_t)NBLK * DIM * DIM;         // 1 MB
  float* sc          = (float*)((char*)d_ws + 2097152);       // 16 B

  // zero qu + rowbest + colmax (contiguous; 0 is identity for both atomics)
  hipMemsetAsync(qu, 0, (size_t)(1179648 + 16384 + 4608) * sizeof(float), stream);

  k_qnorm<<<NQRY, 256, 0, stream>>>(query, q, qh, ql);
  k_ksplit<<<MS, 256, 0, stream>>>(keys, kh, kl);
  k_scalars<<<1, 64, 0, stream>>>(labels, cc, sc);
  k_scoremax<<<dim3(MS / 128, NQRY / 128), 256, 0, stream>>>(qh, ql, kh, kl, rowbest, colmax);
  k_rowscatter<<<NQRY, 256, 0, stream>>>(rowbest, colmax, q, qu);
  k_mem<<<MS, 256, 0, stream>>>(keys, qu, sc, memr);
  k_gram<<<dim3(4, 4, NBLK), 256, 0, stream>>>(memr, Gh, Gl);
  k_read_mfma<<<dim3(NQE / 128, DIM / 128, 2 * NBLK), 256, 0, stream>>>(embS, embT, Gh, Gl, out);
}

// Round 3
// 236.184 us; speedup vs baseline: 3.3912x; 1.2316x over previous
//
#include <hip/hip_runtime.h>
#include <math.h>

// Problem constants (fixed by setup_inputs)
#define NQRY 8192   // queries
#define DIM  256    // d
#define MS   4608   // memory slots m
#define NQE  16384  // Nq embeddings
#define NBLK 8      // m // (C-1) partitions -> 8 blocks of 576
#define PRROWS 576

typedef __attribute__((ext_vector_type(8))) short bf16x8;
typedef __attribute__((ext_vector_type(4))) float f32x4;

// ---- d_out scratch layout (float offsets). All scratch is dead before
// k_read_mfma overwrites the entire output buffer. ----
// q f32          [8192][256]            @ 0
// qh bf16        [8192][256]            @ 2,097,152
// ql bf16        [8192][256]            @ 3,145,728
// kh bf16        [4608][256]            @ 4,194,304
// kl bf16        [4608][256]            @ 4,784,128
// qu f32         [4608][256]            @ 5,373,952
// rowbest u64    [8192]                 @ 6,553,600
// colmax u32     [4608]                 @ 6,569,984
// memr f32       [4608][256]            @ 6,574,592  (ends 7,754,240 < 67,108,864)
// ---- d_ws layout (bytes): ebT bf16 [2][16384][256] @ 0 (16 MB);
//      Gb bf16 [8][256][256] @ 16,777,216 (1 MB); sc f32[4] @ 17,825,792.

// Order-preserving float<->uint mapping for atomicMax on floats
__device__ __forceinline__ unsigned ordf(float f) {
  unsigned u = __float_as_uint(f);
  return (u & 0x80000000u) ? ~u : (u | 0x80000000u);
}
__device__ __forceinline__ float unordf(unsigned u) {
  unsigned b = (u & 0x80000000u) ? (u & 0x7FFFFFFFu) : ~u;
  return __uint_as_float(b);
}
// round-to-nearest-even f32 -> bf16 bits
__device__ __forceinline__ unsigned short bf16rn(float x) {
  unsigned u = __float_as_uint(x);
  unsigned r = u + 0x7FFFu + ((u >> 16) & 1u);
  return (unsigned short)(r >> 16);
}
// split: x = hi(bf16, trunc) + lo(bf16, RN); residual <= 2^-17 |x|
__device__ __forceinline__ void splitbf(float x, unsigned short& h, unsigned short& lo) {
  unsigned u = __float_as_uint(x);
  h = (unsigned short)(u >> 16);
  float hf = __uint_as_float(u & 0xFFFF0000u);
  lo = bf16rn(x - hf);
}

// K0: zero qu + rowbest + colmax (replaces pathologically slow rocclr fill:
// rocprof showed fillBufferAligned of 4690 KB at 31 GB/s = 152 us in-graph)
__global__ __launch_bounds__(256) void k_zero(float4* __restrict__ p, int n4) {
  int i = blockIdx.x * 256 + threadIdx.x;
  if (i < n4) p[i] = float4{0.f, 0.f, 0.f, 0.f};
}

// K1: l2-normalize query rows, emit f32 + bf16 hi/lo splits
__global__ __launch_bounds__(256) void k_qnorm(const float* __restrict__ query,
                                               float* __restrict__ q,
                                               unsigned short* __restrict__ qh,
                                               unsigned short* __restrict__ ql) {
  int i = blockIdx.x, t = threadIdx.x;
  size_t idx = (size_t)i * DIM + t;
  float x = query[idx];
  float v = x * x;
  #pragma unroll
  for (int o = 32; o; o >>= 1) v += __shfl_down(v, o);
  __shared__ float s[4];
  if ((t & 63) == 0) s[t >> 6] = v;
  __syncthreads();
  float ss = (s[0] + s[1]) + (s[2] + s[3]);
  float qq = x / fmaxf(sqrtf(ss), 1e-12f);
  q[idx] = qq;
  unsigned short h, lo;
  splitbf(qq, h, lo);
  qh[idx] = h; ql[idx] = lo;
}

// K2: split keys to bf16 hi/lo
__global__ __launch_bounds__(256) void k_ksplit(const float* __restrict__ keys,
                                                unsigned short* __restrict__ kh,
                                                unsigned short* __restrict__ kl) {
  size_t idx = (size_t)blockIdx.x * 256 + threadIdx.x;
  unsigned short h, lo;
  splitbf(keys[idx], h, lo);
  kh[idx] = h; kl[idx] = lo;
}

// K2b: transpose+convert emb [k][n] f32 -> ebT [n][k] bf16 (RN)
__global__ __launch_bounds__(256) void k_embt(const float* __restrict__ embS,
                                              const float* __restrict__ embT,
                                              unsigned short* __restrict__ ebT) {
  __shared__ float tile[64][33];
  int z = blockIdx.z;
  const float* emb = z ? embT : embS;
  int n0 = blockIdx.x * 32, k0 = blockIdx.y * 64;
  int t = threadIdx.x;
  int kl = t >> 5, nl = t & 31;
  #pragma unroll
  for (int i = 0; i < 8; i++)
    tile[kl * 8 + i][nl] = emb[(size_t)(k0 + kl * 8 + i) * NQE + n0 + nl];
  __syncthreads();
  int nl2 = t >> 3, kq = (t & 7) * 8;
  bf16x8 hv;
  #pragma unroll
  for (int j = 0; j < 8; j++) hv[j] = (short)bf16rn(tile[kq + j][nl2]);
  *(bf16x8*)(ebT + (size_t)z * NQE * DIM + (size_t)(n0 + nl2) * DIM + k0 + kq) = hv;
}

// K3: label-derived scalars (last, count, class_counts[last], active mask)
__global__ void k_scalars(const int* __restrict__ labels,
                          const float* __restrict__ cc,
                          float* __restrict__ sc) {
  int t = threadIdx.x;
  int l = (t < 16) ? labels[t] : (int)0x80000000;
  int mx = l;
  #pragma unroll
  for (int o = 32; o; o >>= 1) mx = max(mx, __shfl_down(mx, o));
  mx = __shfl(mx, 0);
  int cnt = (t < 16 && l == mx) ? 1 : 0;
  #pragma unroll
  for (int o = 32; o; o >>= 1) cnt += __shfl_down(cnt, o);
  unsigned amv = (t < 16) ? (1u << l) : 0u;
  #pragma unroll
  for (int o = 32; o; o >>= 1) amv |= __shfl_down(amv, o);
  if (t == 0) {
    sc[0] = __int_as_float(mx);
    sc[1] = (float)cnt;
    sc[2] = cc[mx];
    sc[3] = __uint_as_float(amv);
  }
}

// K4: fused score GEMM (split-bf16 3-pass MFMA) + row-argmax/col-max epilogue.
__global__ __launch_bounds__(256) void k_scoremax(
    const unsigned short* __restrict__ qh, const unsigned short* __restrict__ ql,
    const unsigned short* __restrict__ kh, const unsigned short* __restrict__ kl,
    unsigned long long* __restrict__ rowbest, unsigned* __restrict__ colmax) {
  __shared__ __align__(16) char smem[65536];
  char* sAh = smem;          char* sAl = smem + 16384;
  char* sBh = smem + 32768;  char* sBl = smem + 49152;
  int tid = threadIdx.x;
  int n0 = blockIdx.x * 128, m0 = blockIdx.y * 128;
  int w = tid >> 6, l = tid & 63;
  int wm = w >> 1, wn = w & 1;
  int lr = l >> 4, lc = l & 15;
  f32x4 acc[4][4] = {};
  for (int kk = 0; kk < 4; kk++) {
    __syncthreads();
    #pragma unroll
    for (int t = 0; t < 4; t++) {
      int c = t * 256 + tid;            // 16B chunk id, 0..1023
      int row = c >> 3, cc = c & 7;
      int ldsb = row * 128 + ((cc * 16) ^ ((row & 7) << 4));  // T2 swizzle
      size_t gA = (size_t)(m0 + row) * DIM + kk * 64 + cc * 8;
      size_t gB = (size_t)(n0 + row) * DIM + kk * 64 + cc * 8;
      *(bf16x8*)(sAh + ldsb) = *(const bf16x8*)(qh + gA);
      *(bf16x8*)(sAl + ldsb) = *(const bf16x8*)(ql + gA);
      *(bf16x8*)(sBh + ldsb) = *(const bf16x8*)(kh + gB);
      *(bf16x8*)(sBl + ldsb) = *(const bf16x8*)(kl + gB);
    }
    __syncthreads();
    #pragma unroll
    for (int st = 0; st < 2; st++) {
      bf16x8 ah[4], al[4], bh[4], bl[4];
      #pragma unroll
      for (int f = 0; f < 4; f++) {
        int ra = wm * 64 + f * 16 + lc;
        int ka = (st * 64 + lr * 16) ^ ((ra & 7) << 4);
        ah[f] = *(const bf16x8*)(sAh + ra * 128 + ka);
        al[f] = *(const bf16x8*)(sAl + ra * 128 + ka);
        int rb = wn * 64 + f * 16 + lc;
        int kb = (st * 64 + lr * 16) ^ ((rb & 7) << 4);
        bh[f] = *(const bf16x8*)(sBh + rb * 128 + kb);
        bl[f] = *(const bf16x8*)(sBl + rb * 128 + kb);
      }
      #pragma unroll
      for (int fm = 0; fm < 4; fm++)
        #pragma unroll
        for (int fn = 0; fn < 4; fn++) {
          acc[fm][fn] = __builtin_amdgcn_mfma_f32_16x16x32_bf16(ah[fm], bh[fn], acc[fm][fn], 0, 0, 0);
          acc[fm][fn] = __builtin_amdgcn_mfma_f32_16x16x32_bf16(ah[fm], bl[fn], acc[fm][fn], 0, 0, 0);
          acc[fm][fn] = __builtin_amdgcn_mfma_f32_16x16x32_bf16(al[fm], bh[fn], acc[fm][fn], 0, 0, 0);
        }
    }
  }
  // epilogue: row argmax (packed u64) + column max
  #pragma unroll
  for (int fm = 0; fm < 4; fm++) {
    #pragma unroll
    for (int rg = 0; rg < 4; rg++) {
      unsigned long long p = 0ull;
      #pragma unroll
      for (int fn = 0; fn < 4; fn++) {
        float v = acc[fm][fn][rg];
        unsigned ng = (unsigned)(n0 + wn * 64 + fn * 16 + lc);
        unsigned long long cand =
            ((unsigned long long)ordf(v) << 32) | (unsigned long long)(0xFFFFFFFFu - ng);
        if (cand > p) p = cand;
      }
      #pragma unroll
      for (int o = 1; o < 16; o <<= 1) {
        unsigned long long t2 = __shfl_xor(p, o);
        if (t2 > p) p = t2;
      }
      if (lc == 0)
        atomicMax(rowbest + (m0 + wm * 64 + fm * 16 + lr * 4 + rg), p);
    }
  }
  #pragma unroll
  for (int fn = 0; fn < 4; fn++) {
    float v = -3.4e38f;
    #pragma unroll
    for (int fm = 0; fm < 4; fm++)
      #pragma unroll
      for (int rg = 0; rg < 4; rg++) v = fmaxf(v, acc[fm][fn][rg]);
    v = fmaxf(v, __shfl_xor(v, 16));
    v = fmaxf(v, __shfl_xor(v, 32));
    if (lr == 0) atomicMax(colmax + (n0 + wn * 64 + fn * 16 + lc), ordf(v));
  }
}

// K5: per-query scatter using rowbest/colmax only (no S).
__global__ __launch_bounds__(256) void k_rowscatter(
    const unsigned long long* __restrict__ rowbest, const unsigned* __restrict__ colmax,
    const float* __restrict__ q, float* __restrict__ qu) {
  int i = blockIdx.x, t = threadIdx.x;
  unsigned long long p = rowbest[i];
  int g = (int)(0xFFFFFFFFu - (unsigned)(p & 0xFFFFFFFFull));
  float sv = unordf((unsigned)(p >> 32));
  float w = expf(sv - unordf(colmax[g]));
  atomicAdd(qu + (size_t)g * DIM + t, w * q[(size_t)i * DIM + t]);
}

// K6: mem = l2norm((temp*keys + qu*active) / temp2)
__global__ __launch_bounds__(256) void k_mem(const float* __restrict__ keys,
                                             const float* __restrict__ qu,
                                             const float* __restrict__ sc,
                                             float* __restrict__ memr) {
  int j = blockIdx.x, t = threadIdx.x;
  int last = __float_as_int(sc[0]);
  float count = sc[1], ccl = sc[2];
  unsigned am = __float_as_uint(sc[3]);
  int cls = j >> 9;  // part = 512
  bool inp = (cls == last);
  float temp = inp ? ccl : 1.0f;
  float quv = ((am >> cls) & 1u) ? qu[(size_t)j * DIM + t] : 0.0f;
  float u = temp * keys[(size_t)j * DIM + t] + quv;
  float temp2 = temp + (inp ? count : 0.0f);
  float v = u / temp2;
  float vv = v * v;
  #pragma unroll
  for (int o = 32; o; o >>= 1) vv += __shfl_down(vv, o);
  __shared__ float s[4];
  if ((t & 63) == 0) s[t >> 6] = vv;
  __syncthreads();
  float ss = (s[0] + s[1]) + (s[2] + s[3]);
  memr[(size_t)j * DIM + t] = v / fmaxf(sqrtf(ss), 1e-12f);
}

// K7: G_b = B_b^T B_b (f32 vector compute), emit single bf16 (RN).
__global__ __launch_bounds__(256) void k_gram(const float* __restrict__ memr,
                                              unsigned short* __restrict__ Gb) {
  __shared__ float As[16][64];
  __shared__ float Bs[16][64];
  int b = blockIdx.z;
  int kxc = blockIdx.x * 64;
  int kyr = blockIdx.y * 64;
  const float* Ab = memr + (size_t)b * PRROWS * DIM;
  int tid = threadIdx.x, tx = tid & 15, ty = tid >> 4;
  int lp = tid >> 4;
  int lk = (tid & 15) * 4;
  float acc[4][4] = {};
  for (int p0 = 0; p0 < PRROWS; p0 += 16) {
    float4 av = *(const float4*)(Ab + (size_t)(p0 + lp) * DIM + kyr + lk);
    float4 bv = *(const float4*)(Ab + (size_t)(p0 + lp) * DIM + kxc + lk);
    __syncthreads();
    *(float4*)&As[lp][lk] = av;
    *(float4*)&Bs[lp][lk] = bv;
    __syncthreads();
    #pragma unroll
    for (int p = 0; p < 16; p++) {
      float a[4], c[4];
      *(float4*)&a[0] = *(const float4*)&As[p][ty * 4];
      *(float4*)&c[0] = *(const float4*)&Bs[p][tx * 4];
      #pragma unroll
      for (int r = 0; r < 4; r++)
        #pragma unroll
        for (int s2 = 0; s2 < 4; s2++)
          acc[r][s2] = fmaf(a[r], c[s2], acc[r][s2]);
    }
  }
  #pragma unroll
  for (int r = 0; r < 4; r++)
    #pragma unroll
    for (int s2 = 0; s2 < 4; s2++)
      Gb[(size_t)b * DIM * DIM + (size_t)(kyr + ty * 4 + r) * DIM + kxc + tx * 4 + s2] =
          bf16rn(acc[r][s2]);
}

// K8: out[eb][n][d] = ebT_e[n,:] @ G_b, 1-pass bf16 MFMA (both operands RN bf16).
__global__ __launch_bounds__(256) void k_read_mfma(
    const unsigned short* __restrict__ ebT, const unsigned short* __restrict__ Gb,
    float* __restrict__ out) {
  __shared__ __align__(16) char smem[32768];
  char* sA = smem;
  char* sB = smem + 16384;
  int tid = threadIdx.x;
  int eb = blockIdx.z;
  const unsigned short* ea = ebT + (size_t)(eb >> 3) * NQE * DIM;
  const unsigned short* gb = Gb + (size_t)(eb & 7) * DIM * DIM;
  int n0 = blockIdx.x * 128, d0 = blockIdx.y * 128;
  int w = tid >> 6, l = tid & 63;
  int wm = w >> 1, wn = w & 1;
  int lr = l >> 4, lc = l & 15;
  f32x4 acc[4][4] = {};
  for (int kk = 0; kk < 4; kk++) {
    __syncthreads();
    #pragma unroll
    for (int t = 0; t < 4; t++) {
      int c = t * 256 + tid;            // 16B chunk id, 0..1023
      int row = c >> 3, cc = c & 7;
      int ldsb = row * 128 + ((cc * 16) ^ ((row & 7) << 4));
      size_t gA = (size_t)(n0 + row) * DIM + kk * 64 + cc * 8;
      size_t gB = (size_t)(d0 + row) * DIM + kk * 64 + cc * 8;
      *(bf16x8*)(sA + ldsb) = *(const bf16x8*)(ea + gA);
      *(bf16x8*)(sB + ldsb) = *(const bf16x8*)(gb + gB);
    }
    __syncthreads();
    #pragma unroll
    for (int st = 0; st < 2; st++) {
      bf16x8 ah[4], bh[4];
      #pragma unroll
      for (int f = 0; f < 4; f++) {
        int ra = wm * 64 + f * 16 + lc;
        int ka = (st * 64 + lr * 16) ^ ((ra & 7) << 4);
        ah[f] = *(const bf16x8*)(sA + ra * 128 + ka);
        int rb = wn * 64 + f * 16 + lc;
        int kb = (st * 64 + lr * 16) ^ ((rb & 7) << 4);
        bh[f] = *(const bf16x8*)(sB + rb * 128 + kb);
      }
      #pragma unroll
      for (int fm = 0; fm < 4; fm++)
        #pragma unroll
        for (int fn = 0; fn < 4; fn++)
          acc[fm][fn] = __builtin_amdgcn_mfma_f32_16x16x32_bf16(ah[fm], bh[fn], acc[fm][fn], 0, 0, 0);
    }
  }
  size_t base = (size_t)eb * NQE * DIM;
  #pragma unroll
  for (int fm = 0; fm < 4; fm++)
    #pragma unroll
    for (int rg = 0; rg < 4; rg++) {
      int n = n0 + wm * 64 + fm * 16 + lr * 4 + rg;
      float* op = out + base + (size_t)n * DIM + d0 + wn * 64 + lc;
      #pragma unroll
      for (int fn = 0; fn < 4; fn++) op[fn * 16] = acc[fm][fn][rg];
    }
}

extern "C" void kernel_launch(void* const* d_in, const int* in_sizes, int n_in,
                              void* d_out, int out_size, void* d_ws, size_t ws_size,
                              hipStream_t stream) {
  const float* query  = (const float*)d_in[0];
  const float* embS   = (const float*)d_in[1];
  const float* embT   = (const float*)d_in[2];
  const float* keys   = (const float*)d_in[3];
  const float* cc     = (const float*)d_in[4];
  const int*   labels = (const int*)d_in[5];
  float* out = (float*)d_out;

  float* q                     = out;
  unsigned short* qh           = (unsigned short*)(out + 2097152);
  unsigned short* ql           = (unsigned short*)(out + 3145728);
  unsigned short* kh           = (unsigned short*)(out + 4194304);
  unsigned short* kl           = (unsigned short*)(out + 4784128);
  float* qu                    = out + 5373952;
  unsigned long long* rowbest  = (unsigned long long*)(out + 6553600);
  unsigned* colmax             = (unsigned*)(out + 6569984);
  float* memr                  = out + 6574592;

  unsigned short* ebT = (unsigned short*)d_ws;                         // 16 MB
  unsigned short* Gb  = (unsigned short*)((char*)d_ws + 16777216);     // 1 MB
  float* sc           = (float*)((char*)d_ws + 17825792);              // 16 B

  // zero qu + rowbest + colmax (contiguous; 0 is identity for both atomics)
  const int n4 = (1179648 + 16384 + 4608) / 4;  // 300160 float4s
  k_zero<<<(n4 + 255) / 256, 256, 0, stream>>>((float4*)qu, n4);

  k_qnorm<<<NQRY, 256, 0, stream>>>(query, q, qh, ql);
  k_ksplit<<<MS, 256, 0, stream>>>(keys, kh, kl);
  k_embt<<<dim3(NQE / 32, DIM / 64, 2), 256, 0, stream>>>(embS, embT, ebT);
  k_scalars<<<1, 64, 0, stream>>>(labels, cc, sc);
  k_scoremax<<<dim3(MS / 128, NQRY / 128), 256, 0, stream>>>(qh, ql, kh, kl, rowbest, colmax);
  k_rowscatter<<<NQRY, 256, 0, stream>>>(rowbest, colmax, q, qu);
  k_mem<<<MS, 256, 0, stream>>>(keys, qu, sc, memr);
  k_gram<<<dim3(4, 4, NBLK), 256, 0, stream>>>(memr, Gb);
  k_read_mfma<<<dim3(NQE / 128, DIM / 128, 2 * NBLK), 256, 0, stream>>>(ebT, Gb, out);
}